// Round 6
// baseline (230.891 us; speedup 1.0000x reference)
//
#include <hip/hip_runtime.h>

typedef __attribute__((ext_vector_type(8))) short short8;
typedef __attribute__((ext_vector_type(4))) float f32x4;

#define NROW 8192
#define D_SZ 512

// workspace byte offsets.
// Region [0, 8388608) holds hb (bf16 H) during the feature phase; after
// combine_feature it is DEAD and the label path reuses it:
#define HB_OFF     0u         // bf16 [8192][512] = 8388608 B   (feature phase)
#define SPARTL_OFF 0u         // f32 [16][256][256] = 4194304 B (label phase, aliases hb)
#define SGRAM_OFF  4194304u   // f32 [256][256] = 262144 B
#define PSUMP_OFF  4456448u   // f32 [32][128] = 16384 B
#define FPART_OFF  4472832u   // f32 [32]
#define POS_OFF    8388608u   // f32 [8192]
#define MPART_OFF  8421376u   // f32 [8][8192] = 262144 B
#define SPARTF_OFF 8683520u   // f32 [8][8192] = 262144 B

// async global->LDS, 16B per lane; LDS dest must be linear (uniform base + lane*16)
#define GLOAD_LDS(gp, lp)                                     \
  __builtin_amdgcn_global_load_lds(                           \
      (const __attribute__((address_space(1))) void*)(gp),    \
      (__attribute__((address_space(3))) void*)(lp), 16, 0, 0)

__device__ __forceinline__ unsigned short f32_to_bf16(float f) {
  unsigned int u = __float_as_uint(f);
  u = (u + 0x7FFFu + ((u >> 16) & 1u)) >> 16;
  return (unsigned short)u;
}

__global__ void convert_kernel(const float* __restrict__ h1, const float* __restrict__ h2,
                               unsigned short* __restrict__ hb) {
  int tid = blockIdx.x * 256 + threadIdx.x;  // float4 id, 1048576 total
  float4 v = (tid < 524288) ? reinterpret_cast<const float4*>(h1)[tid]
                            : reinterpret_cast<const float4*>(h2)[tid - 524288];
  ushort4 o;
  o.x = f32_to_bf16(v.x); o.y = f32_to_bf16(v.y);
  o.z = f32_to_bf16(v.z); o.w = f32_to_bf16(v.w);
  reinterpret_cast<ushort4*>(hb)[tid] = o;
}

// pos[r] = sim(r, partner(r)) = 2*dot(h1_i, h2_i) for r=i and r=i+4096 (symmetric).
// Computed from f32 sources directly; frees the feature kernel of in-loop stores.
__global__ void pos_kernel(const float* __restrict__ h1, const float* __restrict__ h2,
                           float* __restrict__ pos) {
  const int row = blockIdx.x * 4 + (threadIdx.x >> 6);
  const int lane = threadIdx.x & 63;
  const float4* a = reinterpret_cast<const float4*>(h1 + (size_t)row * D_SZ) + lane * 2;
  const float4* b = reinterpret_cast<const float4*>(h2 + (size_t)row * D_SZ) + lane * 2;
  float4 a0 = a[0], a1 = a[1], b0 = b[0], b1 = b[1];
  float d = a0.x * b0.x + a0.y * b0.y + a0.z * b0.z + a0.w * b0.w +
            a1.x * b1.x + a1.y * b1.y + a1.z * b1.z + a1.w * b1.w;
#pragma unroll
  for (int off = 1; off < 64; off <<= 1) d += __shfl_xor(d, off);
  if (lane == 0) {
    pos[row] = 2.f * d;
    pos[row + 4096] = 2.f * d;
  }
}

// ---------------- feature NT-Xent: flash-style LSE over sim = hb hb^T * 2 ----------------
// Geometry identical to r5 (verified): 256x256 block tile, 8 waves (2x4),
// wave tile 128x64, BK=64 double-buffered A+B LDS (128 KB), 1 block/CU,
// involution-swizzled staging (0 bank conflicts measured).
// NEW (T4): counted s_waitcnt vmcnt(8) + raw s_barrier pairs instead of
// __syncthreads() -> next tile's 8 staging loads stay in flight across the
// barrier; no vmcnt(0) drain in the main loop. The loop body issues NO other
// VMEM ops (pos moved to pos_kernel) so vmcnt counts are exact.
__global__ __launch_bounds__(512, 2) void feature_kernel(
    const short* __restrict__ hb,
    float* __restrict__ mpart, float* __restrict__ spart) {
  __shared__ short lds_s[2][2][16384];  // [buf][A=0/B=1][256 rows x 64 k] bf16 swizzled
  const int tid = threadIdx.x;
  const int w = tid >> 6;
  const int lane = tid & 63;
  const int lo16 = lane & 15;
  const int grp = lane >> 4;
  const int lo7 = lo16 & 7;
  const int wr = w >> 2;            // 0..1 row-half
  const int wc = w & 3;             // 0..3 col-quarter
  const int cz = blockIdx.x;        // 0..7 col-chunk (block id % 8 -> XCD id)
  const int bt = blockIdx.y;        // 0..31 row-tile
  const int R0 = bt * 256;
  const int CZ0 = cz * 1024;

  // staging: thread stages chunk (tid&7) of rows {i*64 + (tid>>3)}, i=0..3, per tile.
  // source chunk pre-swizzled by row&7 = (tid>>3)&7 (constant per thread).
  const int srow = tid >> 3;
  const int csrc = (tid & 7) ^ (srow & 7);
  const short* baseA = hb + (size_t)(R0 + srow) * D_SZ + csrc * 8;
  const short* baseB = hb + (size_t)(CZ0 + srow) * D_SZ + csrc * 8;

#define STAGE_STEP(ct_, bk_, buf_) do {                        \
    const short* sa_ = baseA + (bk_) * 64;                     \
    const short* sb_ = baseB + (ct_) * 131072 + (bk_) * 64;    \
    short* da_ = &lds_s[buf_][0][tid * 8];                     \
    short* db_ = &lds_s[buf_][1][tid * 8];                     \
    GLOAD_LDS(sa_, da_);                  GLOAD_LDS(sb_, db_);                  \
    GLOAD_LDS(sa_ + 32768, da_ + 4096);   GLOAD_LDS(sb_ + 32768, db_ + 4096);   \
    GLOAD_LDS(sa_ + 65536, da_ + 8192);   GLOAD_LDS(sb_ + 65536, db_ + 8192);   \
    GLOAD_LDS(sa_ + 98304, da_ + 12288);  GLOAD_LDS(sb_ + 98304, db_ + 12288);  \
  } while (0)

  float mrun[8], srun[8];
#pragma unroll
  for (int rf = 0; rf < 8; ++rf) { mrun[rf] = -INFINITY; srun[rf] = 0.f; }

  f32x4 acc[4][8];
#pragma unroll
  for (int cf = 0; cf < 4; ++cf)
#pragma unroll
    for (int rf = 0; rf < 8; ++rf) acc[cf][rf] = (f32x4){0, 0, 0, 0};

  const int rowbaseA = (wr * 128 + lo16) * 64;  // elem offset of lane's A row
  const int colbaseB = (wc * 64 + lo16) * 64;   // elem offset of lane's B col-row

  STAGE_STEP(0, 0, 0);

#pragma unroll 1
  for (int step = 0; step < 32; ++step) {
    const int ct = step >> 3, bk = step & 7, buf = step & 1;
    // issue next tile's 8 staging loads (safe: readers of buf^1 finished at the
    // end-barrier of step-1, which precedes this point)
    if (step < 31) {
      const int s2 = step + 1;
      STAGE_STEP(s2 >> 3, s2 & 7, buf ^ 1);
      // wait for THIS step's 8 loads only; the 8 just issued stay in flight
      asm volatile("s_waitcnt vmcnt(8)" ::: "memory");
    } else {
      asm volatile("s_waitcnt vmcnt(0)" ::: "memory");
    }
    __builtin_amdgcn_s_barrier();          // all waves' stage-step loads landed
    __builtin_amdgcn_sched_barrier(0);     // no ds_read hoists above this point

    const short* pA = &lds_s[buf][0][0];
    const short* pB = &lds_s[buf][1][0];

#pragma unroll
    for (int ksub = 0; ksub < 2; ++ksub) {
      const int chsw = ((ksub * 4 + grp) ^ lo7) * 8;
      short8 cf_[4], rf_[8];
#pragma unroll
      for (int cf = 0; cf < 4; ++cf)
        cf_[cf] = *reinterpret_cast<const short8*>(&pB[colbaseB + cf * 1024 + chsw]);
#pragma unroll
      for (int rf = 0; rf < 8; ++rf)
        rf_[rf] = *reinterpret_cast<const short8*>(&pA[rowbaseA + rf * 1024 + chsw]);
#pragma unroll
      for (int cf = 0; cf < 4; ++cf)
#pragma unroll
        for (int rf = 0; rf < 8; ++rf)
          acc[cf][rf] = __builtin_amdgcn_mfma_f32_16x16x32_bf16(cf_[cf], rf_[rf],
                                                                acc[cf][rf], 0, 0, 0);
    }

    if (bk == 7) {
      // epilogue for col-tile ct: cols [C0, C0+256)
      const int C0 = CZ0 + ct * 256;
      const bool hd = (C0 == R0);  // diagonal tile: mask sim(r,r)
#pragma unroll
      for (int rf = 0; rf < 8; ++rf) {
        const int row = R0 + wr * 128 + rf * 16 + lo16;
        float v[16];
#pragma unroll
        for (int cf = 0; cf < 4; ++cf)
#pragma unroll
          for (int j = 0; j < 4; ++j) v[cf * 4 + j] = acc[cf][rf][j] * 2.f;
        if (hd) {
#pragma unroll
          for (int cf = 0; cf < 4; ++cf)
#pragma unroll
            for (int j = 0; j < 4; ++j) {
              const int c = C0 + wc * 64 + cf * 16 + grp * 4 + j;
              if (c == row) v[cf * 4 + j] = -INFINITY;
            }
        }
        float tm = v[0];
#pragma unroll
        for (int i = 1; i < 16; ++i) tm = fmaxf(tm, v[i]);
        const float mn = fmaxf(mrun[rf], tm);
        float e = 0.f;
#pragma unroll
        for (int i = 0; i < 16; ++i) e += __expf(v[i] - mn);
        srun[rf] = srun[rf] * __expf(mrun[rf] - mn) + e;
        mrun[rf] = mn;
#pragma unroll
        for (int cf = 0; cf < 4; ++cf) acc[cf][rf] = (f32x4){0, 0, 0, 0};
      }
    }
    __builtin_amdgcn_sched_barrier(0);     // compute may not sink below
    __builtin_amdgcn_s_barrier();          // all reads of buf done -> overwrite ok
  }

  // merge the 4 grp-copies of each row (lanes 16/32 apart hold same row, diff cols)
#pragma unroll
  for (int rf = 0; rf < 8; ++rf) {
#pragma unroll
    for (int off = 16; off <= 32; off <<= 1) {
      float mo = __shfl_xor(mrun[rf], off), so = __shfl_xor(srun[rf], off);
      float mn = fmaxf(mrun[rf], mo);
      srun[rf] = srun[rf] * __expf(mrun[rf] - mn) + so * __expf(mo - mn);
      mrun[rf] = mn;
    }
  }

  // cross-wave (wc) merge via LDS, then write per-chunk partials
  float* marr = reinterpret_cast<float*>(&lds_s[0][0][0]);  // [2][4][8][16]
  float* sarr = marr + 1024;
  if (grp == 0) {
#pragma unroll
    for (int rf = 0; rf < 8; ++rf) {
      const int idx = ((wr * 4 + wc) * 8 + rf) * 16 + lo16;
      marr[idx] = mrun[rf];
      sarr[idx] = srun[rf];
    }
  }
  __syncthreads();
  if (tid < 256) {
    const int row = tid;
    const int wr2 = row >> 7, rf2 = (row >> 4) & 7, lo2 = row & 15;
    float M = -INFINITY, S = 0.f;
#pragma unroll
    for (int wc2 = 0; wc2 < 4; ++wc2) {
      const int idx = ((wr2 * 4 + wc2) * 8 + rf2) * 16 + lo2;
      const float m = marr[idx], s = sarr[idx];
      const float mn = fmaxf(M, m);
      S = S * __expf(M - mn) + s * __expf(m - mn);
      M = mn;
    }
    mpart[cz * NROW + R0 + row] = M;
    spart[cz * NROW + R0 + row] = S;
  }
#undef STAGE_STEP
}

__global__ void combine_feature_kernel(const float* __restrict__ mpart,
                                       const float* __restrict__ spart,
                                       const float* __restrict__ pos,
                                       const float* __restrict__ conf,
                                       float* __restrict__ fpart) {
  __shared__ float red[256];
  int r = blockIdx.x * 256 + threadIdx.x;
  float M = -INFINITY;
#pragma unroll
  for (int k = 0; k < 8; ++k) M = fmaxf(M, mpart[k * NROW + r]);
  float S = 0.f;
#pragma unroll
  for (int k = 0; k < 8; ++k) S += spart[k * NROW + r] * __expf(mpart[k * NROW + r] - M);
  float lse = logf(S) + M;
  float loss = (lse - pos[r]) * conf[r & 4095];
  red[threadIdx.x] = loss;
  __syncthreads();
  for (int s = 128; s > 0; s >>= 1) {
    if (threadIdx.x < s) red[threadIdx.x] += red[threadIdx.x + s];
    __syncthreads();
  }
  if (threadIdx.x == 0) fpart[blockIdx.x] = red[0];
}

// ---------------- label path: S = X^T X, X = [q1 | q2] (4096 x 256), f32 ----------------
// grid 256: kz = b>>4 (16-way split-K), bi = (b>>2)&3, bj = b&3 (64x64 tiles).
// 4x4 micro-tile per thread; partials -> Spart (no atomics).
__global__ __launch_bounds__(256) void label_gemm_kernel(const float* __restrict__ q1,
                                                         const float* __restrict__ q2,
                                                         float* __restrict__ Spart) {
  __shared__ float As[32 * 64];
  __shared__ float Bs[32 * 64];
  const int t = threadIdx.x;
  const int kz = blockIdx.x >> 4;
  const int bi = (blockIdx.x >> 2) & 3;
  const int bj = blockIdx.x & 3;
  const int tx = t & 15, ty = t >> 4;
  float a[4][4];
#pragma unroll
  for (int dr = 0; dr < 4; ++dr)
#pragma unroll
    for (int dc = 0; dc < 4; ++dc) a[dr][dc] = 0.f;

  for (int ch = 0; ch < 8; ++ch) {
    const int kbase = kz * 256 + ch * 32;
    __syncthreads();
#pragma unroll
    for (int i = 0; i < 8; ++i) {
      int e = i * 256 + t;
      int kr = e >> 6, j = e & 63;
      int ca = bi * 64 + j;
      int cb = bj * 64 + j;
      As[kr * 64 + j] = (ca < 128) ? q1[(kbase + kr) * 128 + ca]
                                   : q2[(kbase + kr) * 128 + ca - 128];
      Bs[kr * 64 + j] = (cb < 128) ? q1[(kbase + kr) * 128 + cb]
                                   : q2[(kbase + kr) * 128 + cb - 128];
    }
    __syncthreads();
#pragma unroll 8
    for (int k = 0; k < 32; ++k) {
      float4 Av = *reinterpret_cast<const float4*>(&As[k * 64 + ty * 4]);
      float4 Bv = *reinterpret_cast<const float4*>(&Bs[k * 64 + tx * 4]);
      a[0][0] += Av.x * Bv.x; a[0][1] += Av.x * Bv.y; a[0][2] += Av.x * Bv.z; a[0][3] += Av.x * Bv.w;
      a[1][0] += Av.y * Bv.x; a[1][1] += Av.y * Bv.y; a[1][2] += Av.y * Bv.z; a[1][3] += Av.y * Bv.w;
      a[2][0] += Av.z * Bv.x; a[2][1] += Av.z * Bv.y; a[2][2] += Av.z * Bv.z; a[2][3] += Av.z * Bv.w;
      a[3][0] += Av.w * Bv.x; a[3][1] += Av.w * Bv.y; a[3][2] += Av.w * Bv.z; a[3][3] += Av.w * Bv.w;
    }
  }
  float* outp = Spart + (size_t)kz * 65536;
#pragma unroll
  for (int dr = 0; dr < 4; ++dr) {
    int r = bi * 64 + ty * 4 + dr;
    int c = bj * 64 + tx * 4;
    float4 o = {a[dr][0], a[dr][1], a[dr][2], a[dr][3]};
    *reinterpret_cast<float4*>(&outp[r * 256 + c]) = o;
  }
}

// b<256: combine Spart -> S. b>=256 (32 blocks): column sums of q1/q2 -> psum_part.
__global__ void label_prep_kernel(const float* __restrict__ q1, const float* __restrict__ q2,
                                  const float* __restrict__ Spart, float* __restrict__ S,
                                  float* __restrict__ psum_part) {
  const int b = blockIdx.x, t = threadIdx.x;
  if (b < 256) {
    int e = b * 256 + t;
    float acc = 0.f;
#pragma unroll
    for (int kz = 0; kz < 16; ++kz) acc += Spart[(size_t)kz * 65536 + e];
    S[e] = acc;
  } else {
    __shared__ float sd[256];
    int idx = b - 256;  // 0..31: q = idx>>4, row-block = idx&15
    const float* q = (idx < 16) ? q1 : q2;
    int col = t & 127, rh = t >> 7;
    int rbase = (idx & 15) * 256 + rh;
    float acc = 0.f;
    for (int i = 0; i < 128; ++i) acc += q[(rbase + 2 * i) * 128 + col];
    sd[t] = acc;
    __syncthreads();
    if (t < 128) psum_part[idx * 128 + col] = sd[t] + sd[t + 128];
  }
}

__global__ __launch_bounds__(256) void label_final_kernel(
    const float* __restrict__ S, const float* __restrict__ psum_part,
    const float* __restrict__ fpart, float* __restrict__ out) {
  __shared__ float nrm[256], red[256], redl[256];
  __shared__ float entropy_sh, feat_sh;
  const int t = threadIdx.x;
  nrm[t] = sqrtf(fmaxf(S[t * 257], 0.f));
  const float* pp = psum_part + (t >> 7) * 2048 + (t & 127);
  float v = 0.f;
#pragma unroll
  for (int i = 0; i < 16; ++i) v += pp[i * 128];
  red[t] = v;
  redl[t] = v * logf(fmaxf(v, 1e-30f));
  __syncthreads();
  for (int s = 64; s > 0; s >>= 1) {
    if ((t & 127) < s) { red[t] += red[t + s]; redl[t] += redl[t + s]; }
    __syncthreads();
  }
  if (t == 0) {
    float tot1 = red[0], tot2 = red[128];
    float ne1 = logf(128.f) + (redl[0] / tot1 - logf(tot1));
    float ne2 = logf(128.f) + (redl[128] / tot2 - logf(tot2));
    entropy_sh = ne1 + ne2;
  }
  __syncthreads();
  red[t] = (t < 32) ? fpart[t] : 0.f;
  __syncthreads();
  for (int s = 128; s > 0; s >>= 1) {
    if (t < s) red[t] += red[t + s];
    __syncthreads();
  }
  if (t == 0) feat_sh = red[0];
  __syncthreads();

  const float nr = nrm[t];
  const float* Srow = S + t * 256;
  const int partner = (t + 128) & 255;
  float m = -INFINITY;
  for (int c = 0; c < 256; ++c) {
    if (c == t) continue;
    float sv = Srow[c] / fmaxf(nr * nrm[c], 1e-8f);
    m = fmaxf(m, sv);
  }
  float ssum = 0.f, posv = 0.f;
  for (int c = 0; c < 256; ++c) {
    float sv = Srow[c] / fmaxf(nr * nrm[c], 1e-8f);
    if (c == partner) posv = sv;
    if (c != t) ssum += __expf(sv - m);
  }
  float loss_r = (logf(ssum) + m) - posv;
  __syncthreads();
  red[t] = loss_r;
  __syncthreads();
  for (int s = 128; s > 0; s >>= 1) {
    if (t < s) red[t] += red[t + s];
    __syncthreads();
  }
  if (t == 0)
    out[0] = 0.5f * (feat_sh / 8192.f) + 0.5f * (red[0] / 256.f + entropy_sh);
}

extern "C" void kernel_launch(void* const* d_in, const int* in_sizes, int n_in,
                              void* d_out, int out_size, void* d_ws, size_t ws_size,
                              hipStream_t stream) {
  const float* h1 = (const float*)d_in[0];
  const float* h2 = (const float*)d_in[1];
  const float* q1 = (const float*)d_in[2];
  const float* q2 = (const float*)d_in[3];
  const float* conf = (const float*)d_in[4];
  float* out = (float*)d_out;
  char* ws = (char*)d_ws;

  unsigned short* hb = (unsigned short*)(ws + HB_OFF);
  float* pos    = (float*)(ws + POS_OFF);
  float* mpart  = (float*)(ws + MPART_OFF);
  float* spartf = (float*)(ws + SPARTF_OFF);
  float* SpartL = (float*)(ws + SPARTL_OFF);
  float* Sgram  = (float*)(ws + SGRAM_OFF);
  float* psump  = (float*)(ws + PSUMP_OFF);
  float* fpart  = (float*)(ws + FPART_OFF);

  convert_kernel<<<4096, 256, 0, stream>>>(h1, h2, hb);
  pos_kernel<<<1024, 256, 0, stream>>>(h1, h2, pos);
  feature_kernel<<<dim3(8, 32), 512, 0, stream>>>((const short*)hb, mpart, spartf);
  combine_feature_kernel<<<32, 256, 0, stream>>>(mpart, spartf, pos, conf, fpart);
  // hb region is dead from here on; label path reuses it.
  label_gemm_kernel<<<256, 256, 0, stream>>>(q1, q2, SpartL);
  label_prep_kernel<<<288, 256, 0, stream>>>(q1, q2, SpartL, Sgram, psump);
  label_final_kernel<<<1, 256, 0, stream>>>(Sgram, psump, fpart, out);
}